// Round 1
// 157.919 us; speedup vs baseline: 1.0479x; 1.0479x over previous
//
#include <hip/hip_runtime.h>

#define E_DIM 512
#define N_DIM 512
#define B_DIM 32
#define H_DIM 8
#define D_DIM 8
#define P3    192   // 3 * H * D

typedef _Float16 half_t;
typedef __attribute__((ext_vector_type(2))) _Float16 half2v;
typedef __attribute__((ext_vector_type(4))) _Float16 half4v;
typedef __attribute__((ext_vector_type(8))) _Float16 half8v;
typedef __attribute__((ext_vector_type(4))) float f32x4;

#define XS_STRIDE 520   // ln x-tile stride (halves): 260 dw % 32 = 4 -> uniform banks
#define KB2_STRIDE 20   // zero-padded K row: 8 real + 12 zero halves (40B, 8B-aligned, good banks)
#define KT_STRIDE  532  // K^T row stride in halves (1064B, 8B-aligned, 266dw%32=10 -> spread banks)

// ---------------------------------------------------------------------------
__device__ inline float block_reduce_256(float v) {
    __shared__ float red[4];
    #pragma unroll
    for (int m = 32; m >= 1; m >>= 1) v += __shfl_xor(v, m);
    int w = threadIdx.x >> 6;
    if ((threadIdx.x & 63) == 0) red[w] = v;
    __syncthreads();
    if (threadIdx.x == 0) v = red[0] + red[1] + red[2] + red[3];
    return v;
}

__device__ inline half8v cvt8(float4 a, float4 b) {
    half8v h;
    h[0] = (half_t)a.x; h[1] = (half_t)a.y; h[2] = (half_t)a.z; h[3] = (half_t)a.w;
    h[4] = (half_t)b.x; h[5] = (half_t)b.y; h[6] = (half_t)b.z; h[7] = (half_t)b.w;
    return h;
}

__device__ inline half2v pk2(float a, float b) {
    return __builtin_bit_cast(half2v, __builtin_amdgcn_cvt_pkrtz(a, b));
}

// ---------------------------------------------------------------------------
// K0: prep. WthF = f16(W*g) in MFMA-fragment-coalesced layout:
//   WthF[((ct*16 + k32)*64 + g2*16 + c16)*8 + j] = Wth[p'=ct*16+c16][e=k32*32+g2*8+j]
// so ln_qkv's B-fragment load is WthF + (ct*16+k32)*512 + lane*8 (contiguous).
// colsum[p'] = sum of f16-rounded w; b2[p'] = bias + W·ln_beta.
// Block 0 inits y[b]=bl, c0acc=0.
// ---------------------------------------------------------------------------
__global__ __launch_bounds__(256) void prep_w(const float* __restrict__ Wq,
                        const float* __restrict__ Wk, const float* __restrict__ Wv,
                        const float* __restrict__ gq, const float* __restrict__ gk,
                        const float* __restrict__ gv,
                        const float* __restrict__ bnq, const float* __restrict__ bnk,
                        const float* __restrict__ bnv,
                        const float* __restrict__ bq, const float* __restrict__ bk,
                        const float* __restrict__ bv,
                        const float* __restrict__ bl,
                        half_t* __restrict__ WthF, float* __restrict__ colsum,
                        float* __restrict__ b2, float* __restrict__ y,
                        float* __restrict__ c0acc) {
    int pp = blockIdx.x;     // 192
    int which = pp >> 6, p = pp & 63;
    int ct = pp >> 4, c16 = pp & 15;
    const float* W  = (which == 0) ? Wq  : (which == 1) ? Wk  : Wv;
    const float* g  = (which == 0) ? gq  : (which == 1) ? gk  : gv;
    const float* bn = (which == 0) ? bnq : (which == 1) ? bnk : bnv;
    const float* bb = (which == 0) ? bq  : (which == 1) ? bk  : bv;
    int t = threadIdx.x;
    if (pp == 0) {
        if (t < 32) y[t] = bl[0];
        if (t == 32) c0acc[0] = 0.f;
    }
    float cs = 0.f, dt = 0.f;
    #pragma unroll
    for (int l = 0; l < 2; ++l) {
        int e = t + l * 256;
        float wv = W[p * E_DIM + e];
        half_t wh = (half_t)(wv * g[e]);
        int k32 = e >> 5, g2 = (e >> 3) & 3, j = e & 7;
        WthF[(((size_t)(ct * 16 + k32) * 64) + g2 * 16 + c16) * 8 + j] = wh;
        cs += (float)wh;
        dt += wv * bn[e];
    }
    cs = block_reduce_256(cs);
    __syncthreads();
    dt = block_reduce_256(dt);
    if (t == 0) { colsum[pp] = cs; b2[pp] = dt + bb[p]; }
}

// ---------------------------------------------------------------------------
// K1: blocks 0-1023: fused LN+QKV with LDS-staged x (coalesced loads) and
// coalesced WthF B-fragments. One barrier. Blocks 1024-1055: Wl2 via MFMA.
// ---------------------------------------------------------------------------
__global__ __launch_bounds__(256) void ln_qkv_wl2(const float* __restrict__ x,
                                              const half_t* __restrict__ WthF,
                                              const float* __restrict__ b2,
                                              const float* __restrict__ colsum,
                                              half_t* __restrict__ qkv16,
                                              const float* __restrict__ Wl,
                                              const float* __restrict__ Wo,
                                              const float* __restrict__ bo,
                                              float* __restrict__ Wl2,
                                              float* __restrict__ c0acc) {
    __shared__ half_t Xs[16 * XS_STRIDE];   // 16.25 KB
    __shared__ float stats[16][2];
    if (blockIdx.x < 1024) {
        const int t = threadIdx.x;
        const int lane = t & 63;
        const int w = t >> 6;
        const int g2 = lane >> 4, c16 = lane & 15;
        const int row0 = blockIdx.x * 16;
        // ---- stage x -> f16 LDS (coalesced: 16-lane groups read 256B runs) ----
        {
            const int row = t >> 4, c = t & 15;
            const float4* xrow = (const float4*)(x + (size_t)(row0 + row) * E_DIM);
            float sx = 0.f, sxx = 0.f;
            #pragma unroll
            for (int l = 0; l < 8; ++l) {
                int f4 = c + l * 16;
                float4 a = xrow[f4];
                sx  += a.x + a.y + a.z + a.w;
                sxx += a.x*a.x + a.y*a.y + a.z*a.z + a.w*a.w;
                half4v h;
                h[0] = (half_t)a.x; h[1] = (half_t)a.y;
                h[2] = (half_t)a.z; h[3] = (half_t)a.w;
                *(half4v*)&Xs[row * XS_STRIDE + f4 * 4] = h;
            }
            #pragma unroll
            for (int m = 1; m <= 8; m <<= 1) {
                sx += __shfl_xor(sx, m); sxx += __shfl_xor(sxx, m);
            }
            if (c == 0) {
                float mean = sx * (1.f / E_DIM);
                float var  = sxx * (1.f / E_DIM) - mean * mean;
                stats[row][0] = mean;
                stats[row][1] = rsqrtf(var + 1e-5f);
            }
        }
        __syncthreads();
        // ---- K-loop: A from LDS, B from WthF (lane-contiguous) ----
        f32x4 acc[3] = {{0.f,0.f,0.f,0.f},{0.f,0.f,0.f,0.f},{0.f,0.f,0.f,0.f}};
        const half_t* wf = WthF + (size_t)w * 3 * 16 * 512;
        #pragma unroll 4
        for (int k32 = 0; k32 < 16; ++k32) {
            half8v af = *(const half8v*)&Xs[c16 * XS_STRIDE + k32 * 32 + g2 * 8];
            #pragma unroll
            for (int nt = 0; nt < 3; ++nt) {
                half8v bf = *(const half8v*)(wf + ((size_t)(nt * 16 + k32)) * 512 + lane * 8);
                acc[nt] = __builtin_amdgcn_mfma_f32_16x16x32_f16(af, bf, acc[nt], 0, 0, 0);
            }
        }
        // ---- epilogue: LN correction + scattered f16 stores ----
        #pragma unroll
        for (int nt = 0; nt < 3; ++nt) {
            int pp = w * 48 + nt * 16 + c16;
            float cs = colsum[pp], bb = b2[pp];
            int which = pp >> 6, p = pp & 63;
            int h = p >> 3, d = p & 7;
            half_t* dst0 = qkv16 + (size_t)which * (B_DIM * H_DIM * N_DIM * D_DIM);
            #pragma unroll
            for (int r = 0; r < 4; ++r) {
                int rowi = g2 * 4 + r;
                float val = stats[rowi][1] * (acc[nt][r] - stats[rowi][0] * cs) + bb;
                int ng = row0 + rowi;
                int b = ng >> 9, n = ng & 511;
                dst0[(((size_t)(b * H_DIM + h)) * N_DIM + n) * D_DIM + d] = (half_t)val;
            }
        }
    } else {
        // ---- Wl2 MFMA: blk in [0,32) ----
        const int blk = blockIdx.x - 1024;
        const int t = threadIdx.x;
        const int lane = t & 63;
        const int w = t >> 6;
        const int g2 = lane >> 4, c16 = lane & 15;
        const int n0 = blk * 16;
        const int pcol = w * 16;
        f32x4 acc = {0.f, 0.f, 0.f, 0.f};
        float pc = 0.f;
        const float* arow = Wl + (size_t)(n0 + c16) * E_DIM;
        #pragma unroll 2
        for (int k0 = 0; k0 < E_DIM; k0 += 32) {
            int kbase = k0 + g2 * 8;
            float4 a0 = *(const float4*)(arow + kbase);
            float4 a1 = *(const float4*)(arow + kbase + 4);
            if (w == 0) {
                float4 b0 = *(const float4*)(bo + kbase);
                float4 b1 = *(const float4*)(bo + kbase + 4);
                pc += a0.x*b0.x + a0.y*b0.y + a0.z*b0.z + a0.w*b0.w
                    + a1.x*b1.x + a1.y*b1.y + a1.z*b1.z + a1.w*b1.w;
            }
            half8v af = cvt8(a0, a1);
            half8v bf;
            #pragma unroll
            for (int j = 0; j < 8; ++j)
                bf[j] = (half_t)Wo[(size_t)(kbase + j) * 64 + pcol + c16];
            acc = __builtin_amdgcn_mfma_f32_16x16x32_f16(af, bf, acc, 0, 0, 0);
        }
        int p = pcol + c16, h = p >> 3, d = p & 7;
        #pragma unroll
        for (int r = 0; r < 4; ++r) {
            int n = n0 + g2 * 4 + r;
            Wl2[h * (N_DIM * D_DIM) + n * D_DIM + d] = acc[r];
        }
        if (w == 0) {
            pc += __shfl_xor(pc, 16); pc += __shfl_xor(pc, 32);
            pc += __shfl_xor(pc, 1);  pc += __shfl_xor(pc, 2);
            pc += __shfl_xor(pc, 4);  pc += __shfl_xor(pc, 8);
            if (lane == 0) atomicAdd(c0acc, pc);
        }
    }
}

// ---------------------------------------------------------------------------
// K2: MFMA Hopfield, register-resident P.
// Key identity: for v_mfma_f32_16x16x16_f16 the B-fragment layout
// (B[k=4*(l>>4)+j][col=l&15]) is IDENTICAL to the C/D output layout
// (row=4*(l>>4)+r, col=l&15) of the previous MFMA. So:
//   S[key][q]   = mfma16(A=K rows (k=d, upper half zero-padded), B=Xi^T)
//   U^T[d'][q] += mfma16(A=K^T rows 0..7 + ones row 8, B=exp2(S) in-register)
// -> no LDS round-trip for P, no cross-lane ops, denominators via ones row.
// Per-lane ds_read addresses are loop-invariant; kt offsets fold to immediates.
// LDS: Kb2 20480 + KTb 17024 + Xi 2080 = ~39.6 KB -> 4 blocks/CU (grid 4/CU).
// ---------------------------------------------------------------------------
__global__ __launch_bounds__(256) void hopfield(const half_t* __restrict__ q16,
                                                const half_t* __restrict__ k16,
                                                const half_t* __restrict__ v16,
                                                const float* __restrict__ Wl2,
                                                const float* __restrict__ c0acc,
                                                float* __restrict__ y) {
    __shared__ half_t Kb2[N_DIM * KB2_STRIDE];   // [key][8 real + 12 zero] halves
    __shared__ half_t KTb[16 * KT_STRIDE];       // rows 0-7: K^T (later V^T); row 8: ones; 9-15: don't-care
    __shared__ half_t Xi[128 * 8 + 16];          // [q][d] f16 (pad for tail garbage-reads)
    const int t = threadIdx.x;
    const int lane = t & 63;
    const int w = t >> 6;
    const int g2 = lane >> 4;
    const int c16 = lane & 15;
    const int bh = blockIdx.x >> 2, seg = blockIdx.x & 3;
    const float C = 0.25f * 1.44269504088896f;
    const half_t* kg = k16 + (size_t)bh * (N_DIM * D_DIM);
    const half_t* vg = v16 + (size_t)bh * (N_DIM * D_DIM);
    const half_t* qg = q16 + (size_t)bh * (N_DIM * D_DIM) + seg * 128 * 8;
    const float* wl2p = Wl2 + (bh & 7) * (N_DIM * D_DIM) + seg * 128 * 8;

    {   // stage zero-padded K rows + K^T + ones row (each thread: keys 2t, 2t+1)
        const int j0 = 2 * t;
        half8v r0 = *(const half8v*)(kg + j0 * 8);
        half8v r1 = *(const half8v*)(kg + j0 * 8 + 8);
        const half4v z4 = {};
        half_t* p0 = &Kb2[j0 * KB2_STRIDE];
        half_t* p1 = &Kb2[(j0 + 1) * KB2_STRIDE];
        *(half4v*)(p0)      = __builtin_shufflevector(r0, r0, 0, 1, 2, 3);
        *(half4v*)(p0 + 4)  = __builtin_shufflevector(r0, r0, 4, 5, 6, 7);
        *(half4v*)(p0 + 8)  = z4;
        *(half4v*)(p0 + 12) = z4;
        *(half4v*)(p0 + 16) = z4;
        *(half4v*)(p1)      = __builtin_shufflevector(r1, r1, 0, 1, 2, 3);
        *(half4v*)(p1 + 4)  = __builtin_shufflevector(r1, r1, 4, 5, 6, 7);
        *(half4v*)(p1 + 8)  = z4;
        *(half4v*)(p1 + 12) = z4;
        *(half4v*)(p1 + 16) = z4;
        #pragma unroll
        for (int d = 0; d < 8; ++d) {
            KTb[d * KT_STRIDE + j0]     = r0[d];
            KTb[d * KT_STRIDE + j0 + 1] = r1[d];
        }
        KTb[8 * KT_STRIDE + j0]     = (half_t)1.f;
        KTb[8 * KT_STRIDE + j0 + 1] = (half_t)1.f;
    }
    if (t < 128) {   // stage Xi = C * q
        half8v hq = *(const half8v*)(qg + t * 8);
        half8v h;
        #pragma unroll
        for (int d = 0; d < 8; ++d) h[d] = (half_t)(C * (float)hq[d]);
        *(half8v*)&Xi[t * 8] = h;
    }
    __syncthreads();

    const half_t* akp = &Kb2[c16 * KB2_STRIDE + g2 * 4];  // S A-frag: row=key, k=4*g2+j (zeros pre-padded)
    const half_t* aTp = &KTb[c16 * KT_STRIDE + g2 * 4];   // U A-frag: row=d', k=key (4*g2+j within tile)
    const half4v hz = {};
    float fsum = 0.f;

    for (int it = 0; it < 4; ++it) {
        if (it == 3) {   // swap KTb rows 0-7 to V^T (ones row untouched)
            __syncthreads();
            const int j0 = 2 * t;
            half8v r0 = *(const half8v*)(vg + j0 * 8);
            half8v r1 = *(const half8v*)(vg + j0 * 8 + 8);
            #pragma unroll
            for (int d = 0; d < 8; ++d) {
                KTb[d * KT_STRIDE + j0]     = r0[d];
                KTb[d * KT_STRIDE + j0 + 1] = r1[d];
            }
            __syncthreads();
        }
        // B-frags (Xi^T) for the wave's two query tiles; k=8..15 zeroed
        half4v bx0 = *(const half4v*)&Xi[(w * 32 + c16) * 8 + g2 * 4];
        half4v bx1 = *(const half4v*)&Xi[(w * 32 + 16 + c16) * 8 + g2 * 4];
        if (g2 >= 2) { bx0 = hz; bx1 = hz; }
        f32x4 U0 = {0.f, 0.f, 0.f, 0.f}, U1 = {0.f, 0.f, 0.f, 0.f};
        #pragma unroll 4
        for (int kt = 0; kt < 32; ++kt) {
            half4v ak = *(const half4v*)(akp + kt * (16 * KB2_STRIDE));
            half4v aT = *(const half4v*)(aTp + kt * 16);
            f32x4 Z = {0.f, 0.f, 0.f, 0.f};
            f32x4 S0 = __builtin_amdgcn_mfma_f32_16x16x16f16(ak, bx0, Z, 0, 0, 0);
            f32x4 S1 = __builtin_amdgcn_mfma_f32_16x16x16f16(ak, bx1, Z, 0, 0, 0);
            half2v l0 = pk2(__builtin_amdgcn_exp2f(S0[0]), __builtin_amdgcn_exp2f(S0[1]));
            half2v h0 = pk2(__builtin_amdgcn_exp2f(S0[2]), __builtin_amdgcn_exp2f(S0[3]));
            half4v p0 = __builtin_shufflevector(l0, h0, 0, 1, 2, 3);
            half2v l1 = pk2(__builtin_amdgcn_exp2f(S1[0]), __builtin_amdgcn_exp2f(S1[1]));
            half2v h1 = pk2(__builtin_amdgcn_exp2f(S1[2]), __builtin_amdgcn_exp2f(S1[3]));
            half4v p1 = __builtin_shufflevector(l1, h1, 0, 1, 2, 3);
            U0 = __builtin_amdgcn_mfma_f32_16x16x16f16(aT, p0, U0, 0, 0, 0);
            U1 = __builtin_amdgcn_mfma_f32_16x16x16f16(aT, p1, U1, 0, 0, 0);
        }
        // U'[8][q] (ones row) lives in lane 32+c16, reg 0 -> denom broadcast
        float den0 = __shfl(U0[0], 32 + c16, 64);
        float den1 = __shfl(U1[0], 32 + c16, 64);
        float inv0 = __builtin_amdgcn_rcpf(den0);
        float inv1 = __builtin_amdgcn_rcpf(den1);
        if (it < 3) {
            if (g2 < 2) {   // lanes g2<2 hold d = 4*g2 + r
                half4v h0, h1;
                #pragma unroll
                for (int r = 0; r < 4; ++r) {
                    h0[r] = (half_t)(U0[r] * (C * inv0));
                    h1[r] = (half_t)(U1[r] * (C * inv1));
                }
                *(half4v*)&Xi[(w * 32 + c16) * 8 + g2 * 4]      = h0;
                *(half4v*)&Xi[(w * 32 + 16 + c16) * 8 + g2 * 4] = h1;
            }
        } else {
            if (g2 < 2) {
                float4 w0 = *(const float4*)&wl2p[(w * 32 + c16) * 8 + g2 * 4];
                float4 w1 = *(const float4*)&wl2p[(w * 32 + 16 + c16) * 8 + g2 * 4];
                fsum = inv0 * (U0[0]*w0.x + U0[1]*w0.y + U0[2]*w0.z + U0[3]*w0.w)
                     + inv1 * (U1[0]*w1.x + U1[1]*w1.y + U1[2]*w1.z + U1[3]*w1.w);
            }
        }
    }
    float tot = block_reduce_256(fsum);
    if (t == 0) atomicAdd(&y[bh >> 3], tot);
    if (blockIdx.x == 0 && t < 32) {
        atomicAdd(&y[t], c0acc[0]);
    }
}

// ---------------------------------------------------------------------------
extern "C" void kernel_launch(void* const* d_in, const int* in_sizes, int n_in,
                              void* d_out, int out_size, void* d_ws, size_t ws_size,
                              hipStream_t stream) {
    const float* x   = (const float*)d_in[0];
    const float* g_q = (const float*)d_in[1];
    const float* b_q = (const float*)d_in[2];
    const float* g_k = (const float*)d_in[3];
    const float* b_k = (const float*)d_in[4];
    const float* g_v = (const float*)d_in[5];
    const float* b_v = (const float*)d_in[6];
    const float* Wq  = (const float*)d_in[7];
    const float* bq  = (const float*)d_in[8];
    const float* Wk  = (const float*)d_in[9];
    const float* bk  = (const float*)d_in[10];
    const float* Wv  = (const float*)d_in[11];
    const float* bv  = (const float*)d_in[12];
    const float* Wo  = (const float*)d_in[13];
    const float* bo  = (const float*)d_in[14];
    const float* Wl  = (const float*)d_in[15];
    const float* bl  = (const float*)d_in[16];
    float* out = (float*)d_out;

    float* ws = (float*)d_ws;
    float*  colsum = ws;                      // 192
    float*  b2     = ws + 192;                // 192
    float*  c0acc  = ws + 384;                // 1 (+pad to 64)
    float*  Wl2    = ws + 448;                // 32768
    half_t* WthF   = (half_t*)(ws + 33216);   // 98304 halves = 49152 floats
    half_t* qkv16  = (half_t*)(ws + 82368);   // 3*1048576 halves

    half_t* q16 = qkv16;
    half_t* k16 = qkv16 + 1048576;
    half_t* v16 = qkv16 + 2097152;

    prep_w    <<<192, 256, 0, stream>>>(Wq, Wk, Wv, g_q, g_k, g_v,
                                        b_q, b_k, b_v, bq, bk, bv, bl,
                                        WthF, colsum, b2, out, c0acc);
    ln_qkv_wl2<<<1056, 256, 0, stream>>>(x, WthF, b2, colsum, qkv16,
                                         Wl, Wo, bo, Wl2, c0acc);
    hopfield  <<<1024, 256, 0, stream>>>(q16, k16, v16, Wl2, c0acc, out);
}